// Round 12
// baseline (87.592 us; speedup 1.0000x reference)
//
#include <hip/hip_runtime.h>
#include <math.h>

#define HH 512
#define WW 512
#define NBC 24          // B*C = 8*3
#define TH 64
#define TW 32
#define RAD 4
#define NXT (WW / TW)                 // 16 x-tiles
#define NYT (HH / TH)                 // 8 y-tiles
#define NBLK (NXT * NYT * NBC)        // 3072
#define PI_F 3.14159265358979323846f
#define SMW 36          // LDS row stride (floats)

// Gaussian taps: exp(-0.5*x^2)/sum, x=-4..4 (double-computed, f32-rounded;
// <=1 ulp vs jnp's f32 path).
__device__ __constant__ float GW[9] = {
    1.3383023e-04f, 4.4318484e-03f, 5.3990968e-02f, 2.4197073e-01f,
    3.9894228e-01f, 2.4197073e-01f, 5.3990968e-02f, 4.4318484e-03f,
    1.3383023e-04f
};

// |atan2(y,x)| in [0,pi], branchless, ~3e-7 max error, NaN-free.
__device__ __forceinline__ float abs_atan2_fast(float y, float x)
{
    float ax = fabsf(x), ay = fabsf(y);
    float mx = fmaxf(ax, ay), mn = fminf(ax, ay);
    float t = mn * __builtin_amdgcn_rcpf(fmaxf(mx, 1e-30f));
    float s = t * t;
    float r = -0.01172120f;
    r = fmaf(r, s, 0.05265332f);
    r = fmaf(r, s, -0.11643287f);
    r = fmaf(r, s, 0.19354346f);
    r = fmaf(r, s, -0.33262347f);
    r = fmaf(r, s, 0.99997726f);
    r = r * t;                                  // atan(mn/mx) in [0, pi/4]
    r = (ay > ax) ? (0.5f * PI_F - r) : r;      // undo octant swap
    r = (x < 0.f) ? (PI_F - r) : r;             // quadrant
    return r;
}

__global__ __launch_bounds__(256) void egcl_fused(
    const float* __restrict__ outp,
    const float* __restrict__ tgtp,
    const int*   __restrict__ maskp,
    float*       __restrict__ partials,      // [3][NBLK]
    unsigned int* __restrict__ ticket,
    float*       __restrict__ outv)
{
    __shared__ __align__(16) float smh[TH + 8][SMW];  // 72 rows H-blurred mask
    __shared__ __align__(16) float oT[TH + 2][SMW];   // 66 rows
    __shared__ __align__(16) float tT[TH + 2][SMW];
    __shared__ float red[3][4];
    __shared__ double redd[3][4];
    __shared__ int isLast;

    const int tid = threadIdx.x;

    // XCD-aware bijective swizzle: each XCD gets 3 contiguous z-planes
    const int bid = (int)blockIdx.x;
    const int nb  = (bid & 7) * (NBLK / 8) + (bid >> 3);
    const int xt  = nb & 15;            // x-tile fastest -> row-of-tiles locality
    const int yt  = (nb >> 4) & 7;
    const int z   = nb >> 7;
    const int y0  = yt * TH;
    const int x0  = xt * TW;
    const size_t plane = (size_t)z * (HH * WW);
    const bool xedge = (x0 == 0) || (x0 == WW - TW);

    // ---- mask: global -> registers -> H-blur -> smh. 72 rows x 8 groups ----
    for (int i = tid; i < (TH + 8) * 8; i += 256) {
        int r = i >> 3, cg = (i & 7) << 2;
        int gy = y0 + r - RAD;
        gy = (gy < 0) ? (-gy - 1) : ((gy >= HH) ? (2 * HH - 1 - gy) : gy);
        const int* mrow = maskp + plane + (size_t)gy * WW;
        float win[12];
        if (!xedge) {
            int4 a = *(const int4*)&mrow[x0 + cg - 4];
            int4 b = *(const int4*)&mrow[x0 + cg];
            int4 c = *(const int4*)&mrow[x0 + cg + 4];
            win[0] = (float)a.x; win[1]  = (float)a.y; win[2]  = (float)a.z; win[3]  = (float)a.w;
            win[4] = (float)b.x; win[5]  = (float)b.y; win[6]  = (float)b.z; win[7]  = (float)b.w;
            win[8] = (float)c.x; win[9]  = (float)c.y; win[10] = (float)c.z; win[11] = (float)c.w;
        } else {
            #pragma unroll
            for (int k = 0; k < 12; ++k) {
                int gx = x0 + cg - 4 + k;
                gx = (gx < 0) ? (-gx - 1) : ((gx >= WW) ? (2 * WW - 1 - gx) : gx);
                win[k] = (float)mrow[gx];
            }
        }
        float s0 = 0.f, s1 = 0.f, s2 = 0.f, s3 = 0.f;
        #pragma unroll
        for (int j = 0; j < 9; ++j) {
            float gw = GW[j];
            s0 = fmaf(gw, win[j],     s0);
            s1 = fmaf(gw, win[j + 1], s1);
            s2 = fmaf(gw, win[j + 2], s2);
            s3 = fmaf(gw, win[j + 3], s3);
        }
        *(float4*)&smh[r][cg] = make_float4(s0, s1, s2, s3);
    }

    // ---- o/t tiles: 66 rows x 9 groups of 4 ----
    for (int i = tid; i < (TH + 2) * 9; i += 256) {
        int r = i / 9, g = i - r * 9;
        int gy = y0 + r - 1;
        bool rowin = (gy >= 0) && (gy < HH);
        float4 vo = make_float4(0.f, 0.f, 0.f, 0.f);
        float4 vt = vo;
        if (rowin) {
            const size_t rowbase = plane + (size_t)gy * WW;
            if (!xedge) {
                vo = *(const float4*)&outp[rowbase + (x0 - 1 + 4 * g)];
                vt = *(const float4*)&tgtp[rowbase + (x0 - 1 + 4 * g)];
            } else {
                float a[4], b[4];
                #pragma unroll
                for (int k = 0; k < 4; ++k) {
                    int gx = x0 - 1 + 4 * g + k;
                    bool in = (gx >= 0) && (gx < WW);
                    size_t idx = rowbase + (in ? gx : 0);
                    a[k] = in ? outp[idx] : 0.f;
                    b[k] = in ? tgtp[idx] : 0.f;
                }
                vo = make_float4(a[0], a[1], a[2], a[3]);
                vt = make_float4(b[0], b[1], b[2], b[3]);
            }
        }
        *(float4*)&oT[r][4 * g] = vo;
        *(float4*)&tT[r][4 * g] = vt;
    }
    __syncthreads();

    // ---- compute: thread owns a 2-row x 4-col patch ----
    const int tr  = tid >> 3;           // 0..31
    const int c4  = (tid & 7) << 2;     // 0..28
    const int pr0 = tr << 1;            // output rows pr0, pr0+1

    // V-blur over 10 smh rows -> weights for both rows
    float4 a0 = make_float4(0.f, 0.f, 0.f, 0.f);
    float4 a1 = a0;
    #pragma unroll
    for (int j = 0; j < 10; ++j) {
        float4 m = *(const float4*)&smh[pr0 + j][c4];
        if (j < 9) {
            float gw = GW[j];
            a0.x = fmaf(gw, m.x, a0.x); a0.y = fmaf(gw, m.y, a0.y);
            a0.z = fmaf(gw, m.z, a0.z); a0.w = fmaf(gw, m.w, a0.w);
        }
        if (j > 0) {
            float gw = GW[j - 1];
            a1.x = fmaf(gw, m.x, a1.x); a1.y = fmaf(gw, m.y, a1.y);
            a1.z = fmaf(gw, m.z, a1.z); a1.w = fmaf(gw, m.w, a1.w);
        }
    }
    float wgt[2][4];
    {
        float smv[2][4] = {{a0.x, a0.y, a0.z, a0.w}, {a1.x, a1.y, a1.z, a1.w}};
        #pragma unroll
        for (int p = 0; p < 2; ++p)
            #pragma unroll
            for (int i = 0; i < 4; ++i) {
                float sm = fminf(fmaxf(smv[p][i], 0.f), 1.f);
                float w = 1.f - fabsf(sm - 0.5f) * 2.f;
                wgt[p][i] = fminf(fmaxf(w, 0.f), 1.f);
            }
    }

    // Sobel: 4 LDS rows x 6 cols per image
    float Ro[4][6], Rt[4][6];
    #pragma unroll
    for (int j = 0; j < 4; ++j) {
        *(float4*)&Ro[j][0] = *(const float4*)&oT[pr0 + j][c4];
        *(float2*)&Ro[j][4] = *(const float2*)&oT[pr0 + j][c4 + 4];
        *(float4*)&Rt[j][0] = *(const float4*)&tT[pr0 + j][c4];
        *(float2*)&Rt[j][4] = *(const float2*)&tT[pr0 + j][c4 + 4];
    }

    float gxo[2][4], gyo[2][4], gxt[2][4], gyt[2][4];
    {
        float t0[6], t1[6], u0[6], u1[6];
        #pragma unroll
        for (int j = 0; j < 6; ++j) {
            t0[j] = fmaf(2.f, Ro[1][j], Ro[0][j] + Ro[2][j]);
            t1[j] = fmaf(2.f, Ro[2][j], Ro[1][j] + Ro[3][j]);
            u0[j] = Ro[2][j] - Ro[0][j];
            u1[j] = Ro[3][j] - Ro[1][j];
        }
        #pragma unroll
        for (int i = 0; i < 4; ++i) {
            gxo[0][i] = t0[i + 2] - t0[i];
            gxo[1][i] = t1[i + 2] - t1[i];
            gyo[0][i] = fmaf(2.f, u0[i + 1], u0[i] + u0[i + 2]);
            gyo[1][i] = fmaf(2.f, u1[i + 1], u1[i] + u1[i + 2]);
        }
        #pragma unroll
        for (int j = 0; j < 6; ++j) {
            t0[j] = fmaf(2.f, Rt[1][j], Rt[0][j] + Rt[2][j]);
            t1[j] = fmaf(2.f, Rt[2][j], Rt[1][j] + Rt[3][j]);
            u0[j] = Rt[2][j] - Rt[0][j];
            u1[j] = Rt[3][j] - Rt[1][j];
        }
        #pragma unroll
        for (int i = 0; i < 4; ++i) {
            gxt[0][i] = t0[i + 2] - t0[i];
            gxt[1][i] = t1[i + 2] - t1[i];
            gyt[0][i] = fmaf(2.f, u0[i + 1], u0[i] + u0[i + 2]);
            gyt[1][i] = fmaf(2.f, u1[i + 1], u1[i] + u1[i + 2]);
        }
    }

    float s_w = 0.f, s_mag = 0.f, s_dir = 0.f;
    #pragma unroll
    for (int p = 0; p < 2; ++p) {
        #pragma unroll
        for (int i = 0; i < 4; ++i) {
            float xo = gxo[p][i], yo = gyo[p][i];
            float xt_ = gxt[p][i], yt_ = gyt[p][i];
            float mago = __builtin_amdgcn_sqrtf(fmaf(xo, xo, fmaf(yo, yo, 1e-8f)));
            float magt = __builtin_amdgcn_sqrtf(fmaf(xt_, xt_, fmaf(yt_, yt_, 1e-8f)));
            float cross = yo * xt_ - xo * yt_;
            float dotp  = fmaf(xo, xt_, yo * yt_);
            float dd = abs_atan2_fast(cross, dotp);
            float w = wgt[p][i];
            s_w   += w;
            s_mag += w * fabsf(mago - magt);
            s_dir += dd * w;
        }
    }

    // ---- block reduction ----
    #pragma unroll
    for (int o = 32; o > 0; o >>= 1) {
        s_w   += __shfl_down(s_w,   o, 64);
        s_mag += __shfl_down(s_mag, o, 64);
        s_dir += __shfl_down(s_dir, o, 64);
    }
    const int wid = tid >> 6;
    if ((tid & 63) == 0) { red[0][wid] = s_w; red[1][wid] = s_mag; red[2][wid] = s_dir; }
    __syncthreads();
    if (tid == 0) {
        float p0 = red[0][0] + red[0][1] + red[0][2] + red[0][3];
        float p1 = red[1][0] + red[1][1] + red[1][2] + red[1][3];
        float p2 = red[2][0] + red[2][1] + red[2][2] + red[2][3];
        __hip_atomic_store(&partials[bid],            p0, __ATOMIC_RELAXED, __HIP_MEMORY_SCOPE_AGENT);
        __hip_atomic_store(&partials[NBLK + bid],     p1, __ATOMIC_RELAXED, __HIP_MEMORY_SCOPE_AGENT);
        __hip_atomic_store(&partials[2 * NBLK + bid], p2, __ATOMIC_RELAXED, __HIP_MEMORY_SCOPE_AGENT);
        unsigned int old = __hip_atomic_fetch_add(ticket, 1u, __ATOMIC_ACQ_REL, __HIP_MEMORY_SCOPE_AGENT);
        isLast = (old == (unsigned int)(NBLK - 1));
    }
    __syncthreads();

    // ---- last block performs the final reduction (deterministic order) ----
    if (isLast) {
        double s0 = 0.0, s1 = 0.0, s2 = 0.0;
        for (int i = tid; i < NBLK; i += 256) {
            s0 += (double)__hip_atomic_load(&partials[i],            __ATOMIC_RELAXED, __HIP_MEMORY_SCOPE_AGENT);
            s1 += (double)__hip_atomic_load(&partials[NBLK + i],     __ATOMIC_RELAXED, __HIP_MEMORY_SCOPE_AGENT);
            s2 += (double)__hip_atomic_load(&partials[2 * NBLK + i], __ATOMIC_RELAXED, __HIP_MEMORY_SCOPE_AGENT);
        }
        #pragma unroll
        for (int o = 32; o > 0; o >>= 1) {
            s0 += __shfl_down(s0, o, 64);
            s1 += __shfl_down(s1, o, 64);
            s2 += __shfl_down(s2, o, 64);
        }
        if ((tid & 63) == 0) { redd[0][wid] = s0; redd[1][wid] = s1; redd[2][wid] = s2; }
        __syncthreads();
        if (tid == 0) {
            double Sw   = redd[0][0] + redd[0][1] + redd[0][2] + redd[0][3];
            double Smag = redd[1][0] + redd[1][1] + redd[1][2] + redd[1][3];
            double Sdir = redd[2][0] + redd[2][1] + redd[2][2] + redd[2][3];
            const double N = (double)NBC * HH * WW;
            double mag_loss = Smag / N;
            if (Sw > 0.0) mag_loss = mag_loss / (Sw / N + 1e-8);
            double dir_loss = Sdir;
            if (Sw > 0.0) dir_loss = Sdir / (Sw + 1e-8);
            outv[0] = (float)(mag_loss + dir_loss);
        }
    }
}

extern "C" void kernel_launch(void* const* d_in, const int* in_sizes, int n_in,
                              void* d_out, int out_size, void* d_ws, size_t ws_size,
                              hipStream_t stream)
{
    const float* outp = (const float*)d_in[0];
    const float* tgtp = (const float*)d_in[1];
    const int*   maskp = (const int*)d_in[2];
    float* partials = (float*)d_ws;                     // 3*NBLK floats
    unsigned int* ticket = (unsigned int*)(partials + 3 * NBLK);

    hipMemsetAsync(ticket, 0, sizeof(unsigned int), stream);
    egcl_fused<<<dim3(NBLK, 1, 1), 256, 0, stream>>>(outp, tgtp, maskp,
                                                     partials, ticket, (float*)d_out);
}

// Round 13
// 35.833 us; speedup vs baseline: 2.4444x; 2.4444x over previous
//
#include <hip/hip_runtime.h>
#include <math.h>

#define HH 512
#define WW 512
#define NBC 24          // B*C = 8*3
#define TH 64
#define TW 32
#define RAD 4
#define NXT (WW / TW)                 // 16 x-tiles
#define NYT (HH / TH)                 // 8 y-tiles
#define NBLK (NXT * NYT * NBC)        // 3072
#define PI_F 3.14159265358979323846f
#define SMW 36          // LDS row stride (floats)

// Gaussian taps: exp(-0.5*x^2)/sum, x=-4..4 (double-computed, f32-rounded;
// <=1 ulp vs jnp's f32 path).
__device__ __constant__ float GW[9] = {
    1.3383023e-04f, 4.4318484e-03f, 5.3990968e-02f, 2.4197073e-01f,
    3.9894228e-01f, 2.4197073e-01f, 5.3990968e-02f, 4.4318484e-03f,
    1.3383023e-04f
};

// |atan2(y,x)| in [0,pi], branchless, ~3e-7 max error, NaN-free.
__device__ __forceinline__ float abs_atan2_fast(float y, float x)
{
    float ax = fabsf(x), ay = fabsf(y);
    float mx = fmaxf(ax, ay), mn = fminf(ax, ay);
    float t = mn * __builtin_amdgcn_rcpf(fmaxf(mx, 1e-30f));
    float s = t * t;
    float r = -0.01172120f;
    r = fmaf(r, s, 0.05265332f);
    r = fmaf(r, s, -0.11643287f);
    r = fmaf(r, s, 0.19354346f);
    r = fmaf(r, s, -0.33262347f);
    r = fmaf(r, s, 0.99997726f);
    r = r * t;                                  // atan(mn/mx) in [0, pi/4]
    r = (ay > ax) ? (0.5f * PI_F - r) : r;      // undo octant swap
    r = (x < 0.f) ? (PI_F - r) : r;             // quadrant
    return r;
}

// 512 threads per 64x32 tile: 8 waves/block, 4 blocks/CU -> 32-wave/CU ceiling.
__global__ __launch_bounds__(512) void egcl_fused(
    const float* __restrict__ outp,
    const float* __restrict__ tgtp,
    const int*   __restrict__ maskp,
    float*       __restrict__ partials)  // [3][NBLK]: w, mag, dir
{
    __shared__ __align__(16) float smh[TH + 8][SMW];  // 72 rows H-blurred mask
    __shared__ __align__(16) float oT[TH + 2][SMW];   // 66 rows
    __shared__ __align__(16) float tT[TH + 2][SMW];
    __shared__ float red[3][8];

    const int tid = threadIdx.x;

    // XCD-aware bijective swizzle: each XCD gets 3 contiguous z-planes
    const int bid = (int)blockIdx.x;
    const int nb  = (bid & 7) * (NBLK / 8) + (bid >> 3);
    const int xt  = nb & 15;            // x-tile fastest -> row-of-tiles locality
    const int yt  = (nb >> 4) & 7;
    const int z   = nb >> 7;
    const int y0  = yt * TH;
    const int x0  = xt * TW;
    const size_t plane = (size_t)z * (HH * WW);
    const bool xedge = (x0 == 0) || (x0 == WW - TW);

    // ---- mask: global -> registers -> H-blur -> smh. 72 rows x 8 groups = 576 ----
    for (int i = tid; i < (TH + 8) * 8; i += 512) {
        int r = i >> 3, cg = (i & 7) << 2;
        int gy = y0 + r - RAD;
        gy = (gy < 0) ? (-gy - 1) : ((gy >= HH) ? (2 * HH - 1 - gy) : gy);
        const int* mrow = maskp + plane + (size_t)gy * WW;
        float win[12];
        if (!xedge) {
            int4 a = *(const int4*)&mrow[x0 + cg - 4];
            int4 b = *(const int4*)&mrow[x0 + cg];
            int4 c = *(const int4*)&mrow[x0 + cg + 4];
            win[0] = (float)a.x; win[1]  = (float)a.y; win[2]  = (float)a.z; win[3]  = (float)a.w;
            win[4] = (float)b.x; win[5]  = (float)b.y; win[6]  = (float)b.z; win[7]  = (float)b.w;
            win[8] = (float)c.x; win[9]  = (float)c.y; win[10] = (float)c.z; win[11] = (float)c.w;
        } else {
            #pragma unroll
            for (int k = 0; k < 12; ++k) {
                int gx = x0 + cg - 4 + k;
                gx = (gx < 0) ? (-gx - 1) : ((gx >= WW) ? (2 * WW - 1 - gx) : gx);
                win[k] = (float)mrow[gx];
            }
        }
        float s0 = 0.f, s1 = 0.f, s2 = 0.f, s3 = 0.f;
        #pragma unroll
        for (int j = 0; j < 9; ++j) {
            float gw = GW[j];
            s0 = fmaf(gw, win[j],     s0);
            s1 = fmaf(gw, win[j + 1], s1);
            s2 = fmaf(gw, win[j + 2], s2);
            s3 = fmaf(gw, win[j + 3], s3);
        }
        *(float4*)&smh[r][cg] = make_float4(s0, s1, s2, s3);
    }

    // ---- o/t tiles: 66 rows x 9 groups of 4 = 594 tasks ----
    for (int i = tid; i < (TH + 2) * 9; i += 512) {
        int r = i / 9, g = i - r * 9;
        int gy = y0 + r - 1;
        bool rowin = (gy >= 0) && (gy < HH);
        float4 vo = make_float4(0.f, 0.f, 0.f, 0.f);
        float4 vt = vo;
        if (rowin) {
            const size_t rowbase = plane + (size_t)gy * WW;
            if (!xedge) {
                vo = *(const float4*)&outp[rowbase + (x0 - 1 + 4 * g)];
                vt = *(const float4*)&tgtp[rowbase + (x0 - 1 + 4 * g)];
            } else {
                float a[4], b[4];
                #pragma unroll
                for (int k = 0; k < 4; ++k) {
                    int gx = x0 - 1 + 4 * g + k;
                    bool in = (gx >= 0) && (gx < WW);
                    size_t idx = rowbase + (in ? gx : 0);
                    a[k] = in ? outp[idx] : 0.f;
                    b[k] = in ? tgtp[idx] : 0.f;
                }
                vo = make_float4(a[0], a[1], a[2], a[3]);
                vt = make_float4(b[0], b[1], b[2], b[3]);
            }
        }
        *(float4*)&oT[r][4 * g] = vo;
        *(float4*)&tT[r][4 * g] = vt;
    }
    __syncthreads();   // the ONLY mid-kernel barrier

    // ---- compute: thread owns 1 row x 4 cols ----
    const int r  = tid >> 3;            // 0..63
    const int c4 = (tid & 7) << 2;      // 0..28

    // V-blur over 9 smh rows -> weights
    float4 a0 = make_float4(0.f, 0.f, 0.f, 0.f);
    #pragma unroll
    for (int j = 0; j < 9; ++j) {
        float4 m = *(const float4*)&smh[r + j][c4];
        float gw = GW[j];
        a0.x = fmaf(gw, m.x, a0.x); a0.y = fmaf(gw, m.y, a0.y);
        a0.z = fmaf(gw, m.z, a0.z); a0.w = fmaf(gw, m.w, a0.w);
    }
    float wgt[4];
    {
        float smv[4] = {a0.x, a0.y, a0.z, a0.w};
        #pragma unroll
        for (int i = 0; i < 4; ++i) {
            float sm = fminf(fmaxf(smv[i], 0.f), 1.f);
            float w = 1.f - fabsf(sm - 0.5f) * 2.f;
            wgt[i] = fminf(fmaxf(w, 0.f), 1.f);
        }
    }

    // Sobel: 3 LDS rows x 6 cols per image
    float ao[6], bo[6], co[6], at[6], bt[6], ct[6];
    *(float4*)&ao[0] = *(const float4*)&oT[r    ][c4];
    *(float2*)&ao[4] = *(const float2*)&oT[r    ][c4 + 4];
    *(float4*)&bo[0] = *(const float4*)&oT[r + 1][c4];
    *(float2*)&bo[4] = *(const float2*)&oT[r + 1][c4 + 4];
    *(float4*)&co[0] = *(const float4*)&oT[r + 2][c4];
    *(float2*)&co[4] = *(const float2*)&oT[r + 2][c4 + 4];
    *(float4*)&at[0] = *(const float4*)&tT[r    ][c4];
    *(float2*)&at[4] = *(const float2*)&tT[r    ][c4 + 4];
    *(float4*)&bt[0] = *(const float4*)&tT[r + 1][c4];
    *(float2*)&bt[4] = *(const float2*)&tT[r + 1][c4 + 4];
    *(float4*)&ct[0] = *(const float4*)&tT[r + 2][c4];
    *(float2*)&ct[4] = *(const float2*)&tT[r + 2][c4 + 4];

    // separable Sobel: t = a+2b+c (gx = t[i+2]-t[i]); u = c-a (gy = u[i]+2u[i+1]+u[i+2])
    float to_[6], uo[6], tt_[6], ut[6];
    #pragma unroll
    for (int j = 0; j < 6; ++j) {
        to_[j] = fmaf(2.f, bo[j], ao[j] + co[j]);
        uo[j]  = co[j] - ao[j];
        tt_[j] = fmaf(2.f, bt[j], at[j] + ct[j]);
        ut[j]  = ct[j] - at[j];
    }

    float s_w = 0.f, s_mag = 0.f, s_dir = 0.f;
    #pragma unroll
    for (int i = 0; i < 4; ++i) {
        float xo = to_[i + 2] - to_[i];
        float yo = fmaf(2.f, uo[i + 1], uo[i] + uo[i + 2]);
        float xt_ = tt_[i + 2] - tt_[i];
        float yt_ = fmaf(2.f, ut[i + 1], ut[i] + ut[i + 2]);

        float mago = __builtin_amdgcn_sqrtf(fmaf(xo, xo, fmaf(yo, yo, 1e-8f)));
        float magt = __builtin_amdgcn_sqrtf(fmaf(xt_, xt_, fmaf(yt_, yt_, 1e-8f)));
        float cross = yo * xt_ - xo * yt_;
        float dotp  = fmaf(xo, xt_, yo * yt_);
        float dd = abs_atan2_fast(cross, dotp);
        float w = wgt[i];
        s_w   += w;
        s_mag += w * fabsf(mago - magt);
        s_dir += dd * w;
    }

    // ---- block reduction (8 waves) ----
    #pragma unroll
    for (int o = 32; o > 0; o >>= 1) {
        s_w   += __shfl_down(s_w,   o, 64);
        s_mag += __shfl_down(s_mag, o, 64);
        s_dir += __shfl_down(s_dir, o, 64);
    }
    const int wid = tid >> 6;
    if ((tid & 63) == 0) { red[0][wid] = s_w; red[1][wid] = s_mag; red[2][wid] = s_dir; }
    __syncthreads();
    if (tid == 0) {
        float p0 = 0.f, p1 = 0.f, p2 = 0.f;
        #pragma unroll
        for (int k = 0; k < 8; ++k) { p0 += red[0][k]; p1 += red[1][k]; p2 += red[2][k]; }
        partials[bid]            = p0;
        partials[NBLK + bid]     = p1;
        partials[2 * NBLK + bid] = p2;
    }
}

__global__ __launch_bounds__(256) void egcl_finalize(
    const float* __restrict__ partials, float* __restrict__ out)
{
    __shared__ double red[3][4];
    const int tid = threadIdx.x;
    double s0 = 0.0, s1 = 0.0, s2 = 0.0;
    const float4* p0 = (const float4*)partials;
    const float4* p1 = (const float4*)(partials + NBLK);
    const float4* p2 = (const float4*)(partials + 2 * NBLK);
    for (int i = tid; i < NBLK / 4; i += 256) {
        float4 a = p0[i], b = p1[i], c = p2[i];
        s0 += (double)a.x + (double)a.y + (double)a.z + (double)a.w;
        s1 += (double)b.x + (double)b.y + (double)b.z + (double)b.w;
        s2 += (double)c.x + (double)c.y + (double)c.z + (double)c.w;
    }
    #pragma unroll
    for (int o = 32; o > 0; o >>= 1) {
        s0 += __shfl_down(s0, o, 64);
        s1 += __shfl_down(s1, o, 64);
        s2 += __shfl_down(s2, o, 64);
    }
    const int wid = tid >> 6;
    if ((tid & 63) == 0) { red[0][wid] = s0; red[1][wid] = s1; red[2][wid] = s2; }
    __syncthreads();
    if (tid == 0) {
        double Sw   = red[0][0] + red[0][1] + red[0][2] + red[0][3];
        double Smag = red[1][0] + red[1][1] + red[1][2] + red[1][3];
        double Sdir = red[2][0] + red[2][1] + red[2][2] + red[2][3];
        const double N = (double)NBC * HH * WW;
        double mag_loss = Smag / N;
        if (Sw > 0.0) mag_loss = mag_loss / (Sw / N + 1e-8);
        double dir_loss = Sdir;
        if (Sw > 0.0) dir_loss = Sdir / (Sw + 1e-8);
        out[0] = (float)(mag_loss + dir_loss);
    }
}

extern "C" void kernel_launch(void* const* d_in, const int* in_sizes, int n_in,
                              void* d_out, int out_size, void* d_ws, size_t ws_size,
                              hipStream_t stream)
{
    const float* outp = (const float*)d_in[0];
    const float* tgtp = (const float*)d_in[1];
    const int*   maskp = (const int*)d_in[2];
    float* partials = (float*)d_ws;

    egcl_fused<<<dim3(NBLK, 1, 1), 512, 0, stream>>>(outp, tgtp, maskp, partials);
    egcl_finalize<<<1, 256, 0, stream>>>(partials, (float*)d_out);
}